// Round 7
// baseline (377.419 us; speedup 1.0000x reference)
//
#include <hip/hip_runtime.h>
#include <stdint.h>

#define E_DIM 512
#define NM 24
#define NC 48      // NM * 2 (re/im interleaved)
#define NCOL 96    // q(48) + k(48)
#define B_DIM 16
#define H_DIM 4096
#define NROWS (B_DIM * H_DIM)
#define NPAIR 576  // 24 x 24

typedef _Float16 half8 __attribute__((ext_vector_type(8)));
typedef float f32x4 __attribute__((ext_vector_type(4)));

// ---------- K1: build Ct hi/lo [96][512] f16 + bias d[96] + M[48][512] ----------
// blocks 0..95: C row c (coalesced W reads) + bias via wave-reduce.
// blocks 96..143: M row c-96.
__global__ __launch_bounds__(512)
void k_build(const float* __restrict__ Wq, const float* __restrict__ Wk,
             const float* __restrict__ bq, const float* __restrict__ bk,
             const int* __restrict__ idxq,
             _Float16* __restrict__ Cth, _Float16* __restrict__ Ctl,
             float* __restrict__ dvec, float* __restrict__ M) {
  const int t = threadIdx.x;
  const int bid = blockIdx.x;
  if (bid >= NCOL) {
    // ---- M rows ----
    const int c = bid - NCOL;
    const int j = c >> 1, p = c & 1;
    const int f = idxq[j];
    const float w = (f == 0 ? 1.0f : 2.0f) * (1.0f / (float)E_DIM);
    float s, cc;
    sincospif((float)((f * t) & (E_DIM - 1)) * (1.0f / 256.0f), &s, &cc);
    M[c * E_DIM + t] = p ? (-w * s) : (w * cc);
    return;
  }
  // ---- C row c = bid ----
  __shared__ float tw[E_DIM];
  const int mat = bid / NC;            // 0 = q, 1 = k
  const int c = bid - mat * NC;
  const int j = c >> 1, p = c & 1;
  const int f = idxq[j];
  {
    float s, cc;
    sincospif((float)((f * t) & (E_DIM - 1)) * (1.0f / 256.0f), &s, &cc);
    tw[t] = p ? -s : cc;
  }
  __syncthreads();
  const float* __restrict__ W = mat ? Wk : Wq;
  float acc = 0.0f;
#pragma unroll 8
  for (int o = 0; o < E_DIM; ++o)
    acc = fmaf(W[o * E_DIM + t], tw[o], acc);
  const _Float16 hi = (_Float16)acc;
  Cth[bid * E_DIM + t] = hi;
  Ctl[bid * E_DIM + t] = (_Float16)(acc - (float)hi);
  // bias: wave 0 reduces b . tw
  if (t < 64) {
    const float* __restrict__ bv = mat ? bk : bq;
    float ba = 0.0f;
#pragma unroll
    for (int r = 0; r < 8; ++r) {
      const int o = r * 64 + t;
      ba = fmaf(bv[o], tw[o], ba);
    }
#pragma unroll
    for (int off = 32; off > 0; off >>= 1)
      ba += __shfl_down(ba, off, 64);
    if (t == 0) dvec[bid] = ba;
  }
}

// ---------- K2: fused G-gemm + partial-S ----------
// 4 waves x 32 rows = 128 rows/block, grid 512 (2 blocks/CU, 2 waves/SIMD).
// Explicit 1-iter register prefetch of x. A = Ct f16 hi/lo (L2-hot),
// B = x frags direct from global. Then stage G (128x96) in LDS once,
// accumulate complex S partials for all 576 (x,y) pairs. Emit Gk + Sp.
#define GSTR 100   // LDS row stride (floats)
__global__ __launch_bounds__(256)
void k_gemmG(const float* __restrict__ x, const _Float16* __restrict__ Cth,
             const _Float16* __restrict__ Ctl, const float* __restrict__ dvec,
             float* __restrict__ Gk, float* __restrict__ Sp) {
  __shared__ __align__(16) float gs[128 * GSTR];   // 51.2 KB
  const int t = threadIdx.x;
  const int lane = t & 63;
  const int wv = t >> 6;               // 0..3
  const int rb = blockIdx.x * 128 + wv * 32;
  const int lm = lane & 15;            // A: c-within-tile / B,D: row-within-tile
  const int lk = lane >> 4;            // k-group (and D: c-reg group)
  f32x4 acc[6][2];
#pragma unroll
  for (int mt = 0; mt < 6; ++mt)
#pragma unroll
    for (int nt = 0; nt < 2; ++nt) acc[mt][nt] = (f32x4){0.f, 0.f, 0.f, 0.f};

  // prologue: stage k0 = 0 x-fragments into registers
  float4 xv[2][2];
#pragma unroll
  for (int nt = 0; nt < 2; ++nt) {
    const float* __restrict__ xp = &x[(size_t)(rb + nt * 16 + lm) * E_DIM + lk * 8];
    xv[nt][0] = *(const float4*)xp;
    xv[nt][1] = *(const float4*)(xp + 4);
  }

  for (int k0 = 0; k0 < E_DIM; k0 += 32) {
    // convert current x regs to f16 hi/lo
    half8 xh[2], xl[2];
#pragma unroll
    for (int nt = 0; nt < 2; ++nt) {
      const float vv[8] = {xv[nt][0].x, xv[nt][0].y, xv[nt][0].z, xv[nt][0].w,
                           xv[nt][1].x, xv[nt][1].y, xv[nt][1].z, xv[nt][1].w};
#pragma unroll
      for (int i = 0; i < 8; ++i) {
        const _Float16 h = (_Float16)vv[i];
        xh[nt][i] = h;
        xl[nt][i] = (_Float16)(vv[i] - (float)h);
      }
    }
    // issue next k-tile loads (land during MFMA phase)
    if (k0 + 32 < E_DIM) {
      const int kn = k0 + 32;
#pragma unroll
      for (int nt = 0; nt < 2; ++nt) {
        const float* __restrict__ xp =
            &x[(size_t)(rb + nt * 16 + lm) * E_DIM + kn + lk * 8];
        xv[nt][0] = *(const float4*)xp;
        xv[nt][1] = *(const float4*)(xp + 4);
      }
    }
#pragma unroll
    for (int mt = 0; mt < 6; ++mt) {
      const int arow = mt * 16 + lm;
      const half8 Ah = *(const half8*)&Cth[arow * E_DIM + k0 + lk * 8];
      const half8 Al = *(const half8*)&Ctl[arow * E_DIM + k0 + lk * 8];
#pragma unroll
      for (int nt = 0; nt < 2; ++nt) {
        acc[mt][nt] = __builtin_amdgcn_mfma_f32_16x16x32_f16(Ah, xh[nt], acc[mt][nt], 0, 0, 0);
        acc[mt][nt] = __builtin_amdgcn_mfma_f32_16x16x32_f16(Al, xh[nt], acc[mt][nt], 0, 0, 0);
        acc[mt][nt] = __builtin_amdgcn_mfma_f32_16x16x32_f16(Ah, xl[nt], acc[mt][nt], 0, 0, 0);
      }
    }
  }
  // bias add in-place; write Gk (k-part) to global
#pragma unroll
  for (int mt = 0; mt < 6; ++mt) {
    const int c0 = mt * 16 + lk * 4;
    const float4 bias = *(const float4*)&dvec[c0];
#pragma unroll
    for (int nt = 0; nt < 2; ++nt) {
      acc[mt][nt][0] += bias.x;
      acc[mt][nt][1] += bias.y;
      acc[mt][nt][2] += bias.z;
      acc[mt][nt][3] += bias.w;
      if (mt >= 3) {
        const int r = rb + nt * 16 + lm;
        float4 st;
        st.x = acc[mt][nt][0]; st.y = acc[mt][nt][1];
        st.z = acc[mt][nt][2]; st.w = acc[mt][nt][3];
        *(float4*)&Gk[(size_t)r * NC + (c0 - NC)] = st;
      }
    }
  }
  // ---- stage this block's 128 rows of G into LDS (single stage) ----
#pragma unroll
  for (int mt = 0; mt < 6; ++mt) {
    const int c0 = mt * 16 + lk * 4;
#pragma unroll
    for (int nt = 0; nt < 2; ++nt) {
      const int lrow = wv * 32 + nt * 16 + lm;
      float4 st;
      st.x = acc[mt][nt][0]; st.y = acc[mt][nt][1];
      st.z = acc[mt][nt][2]; st.w = acc[mt][nt][3];
      *(float4*)&gs[lrow * GSTR + c0] = st;
    }
  }
  __syncthreads();
  // ---- partial S for all 576 (x,y) pairs over the 128 rows ----
#pragma unroll
  for (int r = 0; r < 3; ++r) {
    const int i = t + r * 256;
    if (i < NPAIR) {
      const int xx = i / NM, yy = i - xx * NM;
      float ar = 0.f, ai = 0.f;
      for (int h = 0; h < 128; ++h) {
        const float2 q = *(const float2*)&gs[h * GSTR + 2 * xx];
        const float2 k = *(const float2*)&gs[h * GSTR + NC + 2 * yy];
        ar += q.x * k.x - q.y * k.y;   // complex product, no conjugation
        ai += q.x * k.y + q.y * k.x;
      }
      ((float2*)Sp)[(size_t)blockIdx.x * NPAIR + i] = make_float2(ar, ai);
    }
  }
}

// ---------- K3: reduce 32 chunks/batch, |.|, row softmax -> att[b][24][24] ----------
__global__ __launch_bounds__(576)
void k_att(const float* __restrict__ Sp, float* __restrict__ att) {
  __shared__ float mag[NPAIR];
  __shared__ float ex[NPAIR];
  const int t = threadIdx.x;
  const int b = blockIdx.x;
  float sre = 0.0f, sim = 0.0f;
  const float2* in2 = (const float2*)Sp;
  for (int hc = 0; hc < 32; ++hc) {
    const float2 v = in2[(size_t)(b * 32 + hc) * NPAIR + t];
    sre += v.x; sim += v.y;
  }
  mag[t] = sqrtf(sre * sre + sim * sim);
  __syncthreads();
  const int xx = t / NM;
  float m = -1e30f;
  for (int k = 0; k < NM; ++k) m = fmaxf(m, mag[xx * NM + k]);
  const float e = expf(mag[t] - m);
  ex[t] = e;
  __syncthreads();
  float s = 0.0f;
  for (int k = 0; k < NM; ++k) s += ex[xx * NM + k];
  att[b * NPAIR + t] = e / s;
}

// ---------- K4: fused Z + out: out[128 x 256 tile] = (att @ Gk_rows) @ M ----------
#define ZOB 128
#define ZON 256
__global__ __launch_bounds__(512)
void k_zout(const float* __restrict__ Gk, const float* __restrict__ M,
            const float* __restrict__ att, float* __restrict__ out) {
  __shared__ __align__(16) float ms[NC * ZON];      // 48 KB, [k][e] packed
  __shared__ __align__(16) float zs[NC][ZOB + 4];   // stride 132, 25.3 KB
  __shared__ float at[NPAIR];
  const int t = threadIdx.x;
  const int row0 = (blockIdx.x >> 1) * ZOB;
  const int e0 = (blockIdx.x & 1) * ZON;
  const int b = row0 >> 12;
  // issue M loads into regs (in flight across phase B)
  float4 mv[6];
#pragma unroll
  for (int r = 0; r < 6; ++r) {
    const int idx = r * 512 + t;          // f4 idx over [48][256]
    const int k = idx >> 6, ec = idx & 63;
    mv[r] = *(const float4*)&M[k * E_DIM + e0 + ec * 4];
  }
  at[t] = att[b * NPAIR + t];
  if (t < 64) at[512 + t] = att[b * NPAIR + 512 + t];
  __syncthreads();                        // at ready
#pragma unroll
  for (int r = 0; r < 6; ++r) {
    const int idx = r * 512 + t;
    *(float4*)&ms[idx * 4] = mv[r];
  }
  // ---- phase B: Z[row][48] = att-row-mix of Gk row (4 threads per row) ----
  const int zrow = t >> 2;                // 0..127
  const int xg = t & 3;                   // xx-group: xx = xg*6..xg*6+5
  float gk[NC];
  {
    const float4* gk4 = (const float4*)&Gk[(size_t)(row0 + zrow) * NC];
#pragma unroll
    for (int i = 0; i < 12; ++i) {
      const float4 v = gk4[i];
      gk[i * 4 + 0] = v.x; gk[i * 4 + 1] = v.y;
      gk[i * 4 + 2] = v.z; gk[i * 4 + 3] = v.w;
    }
  }
  float z[12];
#pragma unroll
  for (int j = 0; j < 6; ++j) {
    const int xx = xg * 6 + j;
    float zr = 0.0f, zi = 0.0f;
#pragma unroll
    for (int y = 0; y < NM; ++y) {
      const float a = at[xx * NM + y];
      zr = fmaf(a, gk[2 * y], zr);
      zi = fmaf(a, gk[2 * y + 1], zi);
    }
    z[2 * j] = zr; z[2 * j + 1] = zi;
  }
#pragma unroll
  for (int s = 0; s < 12; ++s) zs[xg * 12 + s][zrow] = z[s];
  __syncthreads();                        // zs + ms ready
  // ---- phase C: out tile = zs^T @ ms ----
  const int rr = t >> 4;                  // 0..31 -> rows rr*4..+3
  const int cg = t & 15;                  // cols cg*8..+7 and +128..
  float acc[4][16];
#pragma unroll
  for (int a = 0; a < 4; ++a)
#pragma unroll
    for (int c = 0; c < 16; ++c) acc[a][c] = 0.0f;
#pragma unroll 4
  for (int kk = 0; kk < NC; ++kk) {
    const float4 zv = *(const float4*)&zs[kk][rr * 4];
    const float4 m0 = *(const float4*)&ms[kk * ZON + cg * 8 + 0];
    const float4 m1 = *(const float4*)&ms[kk * ZON + cg * 8 + 4];
    const float4 m2 = *(const float4*)&ms[kk * ZON + cg * 8 + 128];
    const float4 m3 = *(const float4*)&ms[kk * ZON + cg * 8 + 132];
    const float zr[4] = {zv.x, zv.y, zv.z, zv.w};
    const float mr[16] = {m0.x, m0.y, m0.z, m0.w, m1.x, m1.y, m1.z, m1.w,
                          m2.x, m2.y, m2.z, m2.w, m3.x, m3.y, m3.z, m3.w};
#pragma unroll
    for (int a = 0; a < 4; ++a)
#pragma unroll
      for (int c = 0; c < 16; ++c)
        acc[a][c] = fmaf(zr[a], mr[c], acc[a][c]);
  }
#pragma unroll
  for (int a = 0; a < 4; ++a) {
    const int row = row0 + rr * 4 + a;
    float4 v0, v1, v2, v3;
    v0.x = acc[a][0];  v0.y = acc[a][1];  v0.z = acc[a][2];  v0.w = acc[a][3];
    v1.x = acc[a][4];  v1.y = acc[a][5];  v1.z = acc[a][6];  v1.w = acc[a][7];
    v2.x = acc[a][8];  v2.y = acc[a][9];  v2.z = acc[a][10]; v2.w = acc[a][11];
    v3.x = acc[a][12]; v3.y = acc[a][13]; v3.z = acc[a][14]; v3.w = acc[a][15];
    float* o = &out[(size_t)row * E_DIM + e0 + cg * 8];
    *(float4*)(o + 0)   = v0;
    *(float4*)(o + 4)   = v1;
    *(float4*)(o + 128) = v2;
    *(float4*)(o + 132) = v3;
  }
}

extern "C" void kernel_launch(void* const* d_in, const int* in_sizes, int n_in,
                              void* d_out, int out_size, void* d_ws, size_t ws_size,
                              hipStream_t stream) {
  const float* x  = (const float*)d_in[0];
  const float* Wq = (const float*)d_in[1];
  const float* bq = (const float*)d_in[2];
  const float* Wk = (const float*)d_in[3];
  const float* bk = (const float*)d_in[4];
  // d_in[5] (Wv), d_in[6] (bv): dead code in reference, never read
  const int* idxq = (const int*)d_in[7];
  float* out = (float*)d_out;
  float* ws = (float*)d_ws;

  // ws layout (floats): Cth 24576 | Ctl 24576 | d 128 | M 24576 | att 9216 | Sp 589824 | Gk 3145728
  _Float16* Cth = (_Float16*)ws;
  _Float16* Ctl = (_Float16*)(ws + 24576);
  float* dv  = ws + 49152;
  float* M   = ws + 49280;
  float* att = ws + 73856;
  float* Sp  = ws + 83072;
  float* Gk  = ws + 672896;          // total ~14.6 MB of ws

  k_build<<<NCOL + NC, 512, 0, stream>>>(Wq, Wk, bq, bk, idxq, Cth, Ctl, dv, M);
  k_gemmG<<<NROWS / 128, 256, 0, stream>>>(x, Cth, Ctl, dv, Gk, Sp);
  k_att<<<B_DIM, 576, 0, stream>>>(Sp, att);
  k_zout<<<(NROWS / ZOB) * (E_DIM / ZON), 512, 0, stream>>>(Gk, M, att, out);
}

// Round 8
// 356.052 us; speedup vs baseline: 1.0600x; 1.0600x over previous
//
#include <hip/hip_runtime.h>
#include <stdint.h>

#define E_DIM 512
#define NM 24
#define NC 48      // NM * 2 (re/im interleaved)
#define NCOL 96    // q(48) + k(48)
#define B_DIM 16
#define H_DIM 4096
#define NROWS (B_DIM * H_DIM)
#define NPAIR 576  // 24 x 24

typedef _Float16 half8 __attribute__((ext_vector_type(8)));
typedef float f32x4 __attribute__((ext_vector_type(4)));

// async global->LDS, 16B per lane; lds dest must be wave-uniform base (HW adds lane*16)
__device__ __forceinline__ void gload16(const void* g, void* l) {
  __builtin_amdgcn_global_load_lds(
      (const __attribute__((address_space(1))) uint32_t*)g,
      (__attribute__((address_space(3))) uint32_t*)l, 16, 0, 0);
}

// ---------- K1: build Ct hi/lo [96][512] f16 + bias d[96] + M[48][512] ----------
__global__ __launch_bounds__(512)
void k_build(const float* __restrict__ Wq, const float* __restrict__ Wk,
             const float* __restrict__ bq, const float* __restrict__ bk,
             const int* __restrict__ idxq,
             _Float16* __restrict__ Cth, _Float16* __restrict__ Ctl,
             float* __restrict__ dvec, float* __restrict__ M) {
  const int t = threadIdx.x;
  const int bid = blockIdx.x;
  if (bid >= NCOL) {
    // ---- M rows ----
    const int c = bid - NCOL;
    const int j = c >> 1, p = c & 1;
    const int f = idxq[j];
    const float w = (f == 0 ? 1.0f : 2.0f) * (1.0f / (float)E_DIM);
    float s, cc;
    sincospif((float)((f * t) & (E_DIM - 1)) * (1.0f / 256.0f), &s, &cc);
    M[c * E_DIM + t] = p ? (-w * s) : (w * cc);
    return;
  }
  // ---- C row c = bid ----
  __shared__ float tw[E_DIM];
  const int mat = bid / NC;            // 0 = q, 1 = k
  const int c = bid - mat * NC;
  const int j = c >> 1, p = c & 1;
  const int f = idxq[j];
  {
    float s, cc;
    sincospif((float)((f * t) & (E_DIM - 1)) * (1.0f / 256.0f), &s, &cc);
    tw[t] = p ? -s : cc;
  }
  __syncthreads();
  const float* __restrict__ W = mat ? Wk : Wq;
  float acc = 0.0f;
#pragma unroll 8
  for (int o = 0; o < E_DIM; ++o)
    acc = fmaf(W[o * E_DIM + t], tw[o], acc);
  const _Float16 hi = (_Float16)acc;
  Cth[bid * E_DIM + t] = hi;
  Ctl[bid * E_DIM + t] = (_Float16)(acc - (float)hi);
  // bias: wave 0 reduces b . tw
  if (t < 64) {
    const float* __restrict__ bv = mat ? bk : bq;
    float ba = 0.0f;
#pragma unroll
    for (int r = 0; r < 8; ++r) {
      const int o = r * 64 + t;
      ba = fmaf(bv[o], tw[o], ba);
    }
#pragma unroll
    for (int off = 32; off > 0; off >>= 1)
      ba += __shfl_down(ba, off, 64);
    if (t == 0) dvec[bid] = ba;
  }
}

// ---------- K2: fused G-gemm + partial-S, global_load_lds double-buffered ----------
// Per k-tile (32 k): x 16 KB as [lk][128 rows][8 f32], Ct 12 KB as
// [hi/lo][lk][96 rows][8 f16]. 28 chunks of 1 KB; wave w issues chunks 7w..7w+6.
// 2-phase: issue next tile, compute current, barrier (drains vmcnt).
#define GSTR 100            // S-phase LDS row stride (floats)
#define TILE_B 28672        // 16 KB x + 12 KB ct
__global__ __launch_bounds__(256)
void k_gemmG(const float* __restrict__ x, const _Float16* __restrict__ Cth,
             const _Float16* __restrict__ Ctl, const float* __restrict__ dvec,
             float* __restrict__ Gk, float* __restrict__ Sp) {
  __shared__ __align__(16) uint8_t smem[2 * TILE_B];   // 56 KB; aliased as gs after K-loop
  const int t = threadIdx.x;
  const int lane = t & 63;
  const int wv = t >> 6;               // 0..3
  const int rb = blockIdx.x * 128;
  const int wrow0 = wv * 32;
  const int lm = lane & 15;            // A: c-sub / B,D: row-sub
  const int lk = lane >> 4;            // k-group (and D: c-reg group)

  // per-thread staging descriptors for this wave's 7 chunks
  const char* srcp[7];
  int ksc[7];
  int ldso[7];
#pragma unroll
  for (int j = 0; j < 7; ++j) {
    const int c = wv * 7 + j;
    ldso[j] = c * 1024;
    if (c < 16) {                      // x chunk: lk=c>>2, rows (c&3)*32 + lane>>1
      const int xlk = c >> 2;
      const int r = (c & 3) * 32 + (lane >> 1);
      const int h = lane & 1;
      srcp[j] = (const char*)(x + (size_t)(rb + r) * E_DIM + xlk * 8 + h * 4);
      ksc[j] = 4;                      // f32: k0*4 bytes
    } else {                           // Ct chunk
      const int g = (c - 16) * 64 + lane;
      const int part = g / 384;
      const int rem = g - part * 384;
      const int clk = rem / 96;
      const int row = rem - clk * 96;
      srcp[j] = (const char*)((part ? Ctl : Cth) + row * E_DIM + clk * 8);
      ksc[j] = 2;                      // f16: k0*2 bytes
    }
  }

  f32x4 acc[6][2];
#pragma unroll
  for (int mt = 0; mt < 6; ++mt)
#pragma unroll
    for (int nt = 0; nt < 2; ++nt) acc[mt][nt] = (f32x4){0.f, 0.f, 0.f, 0.f};

  // prologue: stage k-tile 0 into buffer 0
#pragma unroll
  for (int j = 0; j < 7; ++j)
    gload16(srcp[j], smem + ldso[j]);
  __syncthreads();                     // drains vmcnt -> tile 0 resident

  for (int kt = 0; kt < 16; ++kt) {
    const int par = kt & 1;
    if (kt < 15) {                     // issue next tile (overlaps compute)
      const int kn = (kt + 1) * 32;
#pragma unroll
      for (int j = 0; j < 7; ++j)
        gload16(srcp[j] + kn * ksc[j], smem + (par ^ 1) * TILE_B + ldso[j]);
    }
    const float* xb = (const float*)(smem + par * TILE_B);
    const _Float16* cb = (const _Float16*)(smem + par * TILE_B + 16384);
    half8 xh[2], xl[2];
#pragma unroll
    for (int nt = 0; nt < 2; ++nt) {
      const float* xp = xb + lk * 1024 + (wrow0 + nt * 16 + lm) * 8;
      const float4 a = *(const float4*)xp;
      const float4 b = *(const float4*)(xp + 4);
      const float vv[8] = {a.x, a.y, a.z, a.w, b.x, b.y, b.z, b.w};
#pragma unroll
      for (int i = 0; i < 8; ++i) {
        const _Float16 hh = (_Float16)vv[i];
        xh[nt][i] = hh;
        xl[nt][i] = (_Float16)(vv[i] - (float)hh);
      }
    }
#pragma unroll
    for (int mt = 0; mt < 6; ++mt) {
      const half8 Ah = *(const half8*)(cb + lk * 768 + (mt * 16 + lm) * 8);
      const half8 Al = *(const half8*)(cb + 3072 + lk * 768 + (mt * 16 + lm) * 8);
#pragma unroll
      for (int nt = 0; nt < 2; ++nt) {
        acc[mt][nt] = __builtin_amdgcn_mfma_f32_16x16x32_f16(Ah, xh[nt], acc[mt][nt], 0, 0, 0);
        acc[mt][nt] = __builtin_amdgcn_mfma_f32_16x16x32_f16(Al, xh[nt], acc[mt][nt], 0, 0, 0);
        acc[mt][nt] = __builtin_amdgcn_mfma_f32_16x16x32_f16(Ah, xl[nt], acc[mt][nt], 0, 0, 0);
      }
    }
    __syncthreads();                   // all waves done reading buf[par]; next tile drained
  }

  // ---- epilogue: bias, Gk write, stage G in LDS (aliased), partial-S ----
  float* gs = (float*)smem;
#pragma unroll
  for (int mt = 0; mt < 6; ++mt) {
    const int c0 = mt * 16 + lk * 4;
    const float4 bias = *(const float4*)&dvec[c0];
#pragma unroll
    for (int nt = 0; nt < 2; ++nt) {
      acc[mt][nt][0] += bias.x;
      acc[mt][nt][1] += bias.y;
      acc[mt][nt][2] += bias.z;
      acc[mt][nt][3] += bias.w;
      const int lrow = wrow0 + nt * 16 + lm;
      float4 st;
      st.x = acc[mt][nt][0]; st.y = acc[mt][nt][1];
      st.z = acc[mt][nt][2]; st.w = acc[mt][nt][3];
      if (mt >= 3)
        *(float4*)&Gk[(size_t)(rb + lrow) * NC + (c0 - NC)] = st;
      *(float4*)&gs[lrow * GSTR + c0] = st;
    }
  }
  __syncthreads();
  // ---- partial S for all 576 (x,y) pairs over the 128 rows ----
#pragma unroll
  for (int r = 0; r < 3; ++r) {
    const int i = t + r * 256;
    if (i < NPAIR) {
      const int xx = i / NM, yy = i - xx * NM;
      float ar = 0.f, ai = 0.f;
      for (int h = 0; h < 128; ++h) {
        const float2 q = *(const float2*)&gs[h * GSTR + 2 * xx];
        const float2 k = *(const float2*)&gs[h * GSTR + NC + 2 * yy];
        ar += q.x * k.x - q.y * k.y;   // complex product, no conjugation
        ai += q.x * k.y + q.y * k.x;
      }
      ((float2*)Sp)[(size_t)blockIdx.x * NPAIR + i] = make_float2(ar, ai);
    }
  }
}

// ---------- K3: reduce 32 chunks/batch, |.|, row softmax -> att[b][24][24] ----------
__global__ __launch_bounds__(576)
void k_att(const float* __restrict__ Sp, float* __restrict__ att) {
  __shared__ float mag[NPAIR];
  __shared__ float ex[NPAIR];
  const int t = threadIdx.x;
  const int b = blockIdx.x;
  float sre = 0.0f, sim = 0.0f;
  const float2* in2 = (const float2*)Sp;
  for (int hc = 0; hc < 32; ++hc) {
    const float2 v = in2[(size_t)(b * 32 + hc) * NPAIR + t];
    sre += v.x; sim += v.y;
  }
  mag[t] = sqrtf(sre * sre + sim * sim);
  __syncthreads();
  const int xx = t / NM;
  float m = -1e30f;
  for (int k = 0; k < NM; ++k) m = fmaxf(m, mag[xx * NM + k]);
  const float e = expf(mag[t] - m);
  ex[t] = e;
  __syncthreads();
  float s = 0.0f;
  for (int k = 0; k < NM; ++k) s += ex[xx * NM + k];
  att[b * NPAIR + t] = e / s;
}

// ---------- K4: fused Z + out: out[128 x 256 tile] = (att @ Gk_rows) @ M ----------
#define ZOB 128
#define ZON 256
__global__ __launch_bounds__(512)
void k_zout(const float* __restrict__ Gk, const float* __restrict__ M,
            const float* __restrict__ att, float* __restrict__ out) {
  __shared__ __align__(16) float ms[NC * ZON];      // 48 KB, [k][e] packed
  __shared__ __align__(16) float zs[NC][ZOB + 4];   // stride 132, 25.3 KB
  __shared__ float at[NPAIR];
  const int t = threadIdx.x;
  const int row0 = (blockIdx.x >> 1) * ZOB;
  const int e0 = (blockIdx.x & 1) * ZON;
  const int b = row0 >> 12;
  // issue M loads into regs (in flight across phase B)
  float4 mv[6];
#pragma unroll
  for (int r = 0; r < 6; ++r) {
    const int idx = r * 512 + t;          // f4 idx over [48][256]
    const int k = idx >> 6, ec = idx & 63;
    mv[r] = *(const float4*)&M[k * E_DIM + e0 + ec * 4];
  }
  at[t] = att[b * NPAIR + t];
  if (t < 64) at[512 + t] = att[b * NPAIR + 512 + t];
  __syncthreads();                        // at ready
#pragma unroll
  for (int r = 0; r < 6; ++r) {
    const int idx = r * 512 + t;
    *(float4*)&ms[idx * 4] = mv[r];
  }
  // ---- phase B: Z[row][48] = att-row-mix of Gk row (4 threads per row) ----
  const int zrow = t >> 2;                // 0..127
  const int xg = t & 3;                   // xx-group: xx = xg*6..xg*6+5
  float gk[NC];
  {
    const float4* gk4 = (const float4*)&Gk[(size_t)(row0 + zrow) * NC];
#pragma unroll
    for (int i = 0; i < 12; ++i) {
      const float4 v = gk4[i];
      gk[i * 4 + 0] = v.x; gk[i * 4 + 1] = v.y;
      gk[i * 4 + 2] = v.z; gk[i * 4 + 3] = v.w;
    }
  }
  float z[12];
#pragma unroll
  for (int j = 0; j < 6; ++j) {
    const int xx = xg * 6 + j;
    float zr = 0.0f, zi = 0.0f;
#pragma unroll
    for (int y = 0; y < NM; ++y) {
      const float a = at[xx * NM + y];
      zr = fmaf(a, gk[2 * y], zr);
      zi = fmaf(a, gk[2 * y + 1], zi);
    }
    z[2 * j] = zr; z[2 * j + 1] = zi;
  }
#pragma unroll
  for (int s = 0; s < 12; ++s) zs[xg * 12 + s][zrow] = z[s];
  __syncthreads();                        // zs + ms ready
  // ---- phase C: out tile = zs^T @ ms ----
  const int rr = t >> 4;                  // 0..31 -> rows rr*4..+3
  const int cg = t & 15;                  // cols cg*8..+7 and +128..
  float acc[4][16];
#pragma unroll
  for (int a = 0; a < 4; ++a)
#pragma unroll
    for (int c = 0; c < 16; ++c) acc[a][c] = 0.0f;
#pragma unroll 4
  for (int kk = 0; kk < NC; ++kk) {
    const float4 zv = *(const float4*)&zs[kk][rr * 4];
    const float4 m0 = *(const float4*)&ms[kk * ZON + cg * 8 + 0];
    const float4 m1 = *(const float4*)&ms[kk * ZON + cg * 8 + 4];
    const float4 m2 = *(const float4*)&ms[kk * ZON + cg * 8 + 128];
    const float4 m3 = *(const float4*)&ms[kk * ZON + cg * 8 + 132];
    const float zr[4] = {zv.x, zv.y, zv.z, zv.w};
    const float mr[16] = {m0.x, m0.y, m0.z, m0.w, m1.x, m1.y, m1.z, m1.w,
                          m2.x, m2.y, m2.z, m2.w, m3.x, m3.y, m3.z, m3.w};
#pragma unroll
    for (int a = 0; a < 4; ++a)
#pragma unroll
      for (int c = 0; c < 16; ++c)
        acc[a][c] = fmaf(zr[a], mr[c], acc[a][c]);
  }
#pragma unroll
  for (int a = 0; a < 4; ++a) {
    const int row = row0 + rr * 4 + a;
    float4 v0, v1, v2, v3;
    v0.x = acc[a][0];  v0.y = acc[a][1];  v0.z = acc[a][2];  v0.w = acc[a][3];
    v1.x = acc[a][4];  v1.y = acc[a][5];  v1.z = acc[a][6];  v1.w = acc[a][7];
    v2.x = acc[a][8];  v2.y = acc[a][9];  v2.z = acc[a][10]; v2.w = acc[a][11];
    v3.x = acc[a][12]; v3.y = acc[a][13]; v3.z = acc[a][14]; v3.w = acc[a][15];
    float* o = &out[(size_t)row * E_DIM + e0 + cg * 8];
    *(float4*)(o + 0)   = v0;
    *(float4*)(o + 4)   = v1;
    *(float4*)(o + 128) = v2;
    *(float4*)(o + 132) = v3;
  }
}

extern "C" void kernel_launch(void* const* d_in, const int* in_sizes, int n_in,
                              void* d_out, int out_size, void* d_ws, size_t ws_size,
                              hipStream_t stream) {
  const float* x  = (const float*)d_in[0];
  const float* Wq = (const float*)d_in[1];
  const float* bq = (const float*)d_in[2];
  const float* Wk = (const float*)d_in[3];
  const float* bk = (const float*)d_in[4];
  // d_in[5] (Wv), d_in[6] (bv): dead code in reference, never read
  const int* idxq = (const int*)d_in[7];
  float* out = (float*)d_out;
  float* ws = (float*)d_ws;

  // ws layout (floats): Cth 24576 | Ctl 24576 | d 128 | M 24576 | att 9216 | Sp 589824 | Gk 3145728
  _Float16* Cth = (_Float16*)ws;
  _Float16* Ctl = (_Float16*)(ws + 24576);
  float* dv  = ws + 49152;
  float* M   = ws + 49280;
  float* att = ws + 73856;
  float* Sp  = ws + 83072;
  float* Gk  = ws + 672896;          // total ~14.6 MB of ws

  k_build<<<NCOL + NC, 512, 0, stream>>>(Wq, Wk, bq, bk, idxq, Cth, Ctl, dv, M);
  k_gemmG<<<NROWS / 128, 256, 0, stream>>>(x, Cth, Ctl, dv, Gk, Sp);
  k_att<<<B_DIM, 576, 0, stream>>>(Sp, att);
  k_zout<<<(NROWS / ZOB) * (E_DIM / ZON), 512, 0, stream>>>(Gk, M, att, out);
}